// Round 1
// baseline (1509.878 us; speedup 1.0000x reference)
//
#include <hip/hip_runtime.h>
#include <cmath>

// Problem constants
#define CN   256   // channels (N_DIST)
#define HN   256   // H
#define WN   192   // W
#define KN   129   // kernel taps
#define RN   64    // radius
#define SN   256   // padded size
#define PADN 32    // (SN - WN)/2
#define TH   16    // outputs per thread along conv axis

// ---------------- conv along H (axis 1) ----------------
// y[c,h,x] = sum_k in[c, h+k-64, x] * kern[c,k], zero pad.
// block: 192 threads (one per x), each computes TH outputs along h.
__global__ __launch_bounds__(192) void conv_h_k(const float* __restrict__ in,
                                                const float* __restrict__ kern,
                                                float* __restrict__ out) {
    const int x  = threadIdx.x;          // 0..191
    const int h0 = blockIdx.x * TH;      // 0..240
    const int c  = blockIdx.y;
    const float* __restrict__ krow = kern + c * KN;
    const float* __restrict__ base = in + ((size_t)c * HN) * WN + x;
    float acc[TH];
#pragma unroll
    for (int t = 0; t < TH; ++t) acc[t] = 0.f;

    // prologue: j = 0 .. TH-2  (only src>=0 can fail)
    for (int j = 0; j < TH - 1; ++j) {
        int src = h0 + j - RN;
        float v = (src >= 0) ? base[(size_t)src * WN] : 0.f;
        for (int t = 0; t <= j; ++t) acc[t] = fmaf(v, krow[j - t], acc[t]);
    }
    // main: j = TH-1 .. KN-1, all TH outputs active
    for (int j = TH - 1; j < KN; ++j) {
        int src = h0 + j - RN;
        float v = (src >= 0 && src < HN) ? base[(size_t)src * WN] : 0.f;
#pragma unroll
        for (int t = 0; t < TH; ++t) acc[t] = fmaf(v, krow[j - t], acc[t]);
    }
    // epilogue: j = KN .. KN+TH-2 (only src<HN can fail)
    for (int j = KN; j < KN + TH - 1; ++j) {
        int src = h0 + j - RN;
        float v = (src < HN) ? base[(size_t)src * WN] : 0.f;
        for (int t = j - KN + 1; t < TH; ++t) acc[t] = fmaf(v, krow[j - t], acc[t]);
    }
    float* __restrict__ ob = out + ((size_t)c * HN + h0) * WN + x;
#pragma unroll
    for (int t = 0; t < TH; ++t) ob[(size_t)t * WN] = acc[t];
}

// ---------------- conv along W (last axis), width WD ----------------
// block: 16 rows x (WD/TH) slots; each thread computes TH contiguous outputs.
template <int WD, bool ACC>
__global__ void conv_w_k(const float* __restrict__ in,
                         const float* __restrict__ kern,
                         float* __restrict__ out) {
    constexpr int SLOTS = WD / TH;       // 12 (WD=192) or 16 (WD=256)
    const int tid = threadIdx.x;
    const int r   = tid / SLOTS;         // 0..15
    const int xs  = tid % SLOTS;
    const int h   = blockIdx.x * 16 + r; // 0..255
    const int c   = blockIdx.y;
    const int x0  = xs * TH;
    const float* __restrict__ krow = kern + c * KN;
    const float* __restrict__ row  = in + ((size_t)c * HN + h) * WD;
    float acc[TH];
#pragma unroll
    for (int t = 0; t < TH; ++t) acc[t] = 0.f;

    for (int j = 0; j < TH - 1; ++j) {
        int src = x0 + j - RN;
        float v = (src >= 0) ? row[src] : 0.f;
        for (int t = 0; t <= j; ++t) acc[t] = fmaf(v, krow[j - t], acc[t]);
    }
    for (int j = TH - 1; j < KN; ++j) {
        int src = x0 + j - RN;
        float v = (src >= 0 && src < WD) ? row[src] : 0.f;
#pragma unroll
        for (int t = 0; t < TH; ++t) acc[t] = fmaf(v, krow[j - t], acc[t]);
    }
    for (int j = KN; j < KN + TH - 1; ++j) {
        int src = x0 + j - RN;
        float v = (src < WD) ? row[src] : 0.f;
        for (int t = j - KN + 1; t < TH; ++t) acc[t] = fmaf(v, krow[j - t], acc[t]);
    }
    float* __restrict__ orow = out + ((size_t)c * HN + h) * WD + x0;
#pragma unroll
    for (int t = 0; t < TH; ++t) {
        if (ACC) orow[t] += acc[t];
        else     orow[t]  = acc[t];
    }
}

// ---------------- forward rotate of implicitly-padded C ----------------
// out[c,i,j] (SN x SN) = bilinear sample of padded(C) at rotated coords.
// padded(C)[y,p] = C[y, p-PADN] if p in [PADN, PADN+WN) else 0; zero outside grid.
__global__ __launch_bounds__(256) void rot_fwd_k(const float* __restrict__ Cin,
                                                 float* __restrict__ out,
                                                 float ca, float sa) {
    const int j = blockIdx.x * 32 + threadIdx.x;  // 0..255
    const int i = blockIdx.y * 8 + threadIdx.y;   // 0..255
    const int c = blockIdx.z;
    const float cc = (SN - 1) * 0.5f;             // 127.5
    float yy = (float)i - cc, xx = (float)j - cc;
    float sy = ca * yy + sa * xx + cc;
    float sx = -sa * yy + ca * xx + cc;
    float y0f = floorf(sy), x0f = floorf(sx);
    float fy = sy - y0f, fx = sx - x0f;
    int y0 = (int)y0f, x0 = (int)x0f;
    const float* __restrict__ base = Cin + (size_t)c * HN * WN;
    auto g = [&](int yi, int xi) -> float {
        int p = xi - PADN;
        return (yi >= 0 && yi < SN && p >= 0 && p < WN)
                   ? base[(size_t)yi * WN + p] : 0.f;
    };
    float v = g(y0, x0) * (1.f - fy) * (1.f - fx)
            + g(y0, x0 + 1) * (1.f - fy) * fx
            + g(y0 + 1, x0) * fy * (1.f - fx)
            + g(y0 + 1, x0 + 1) * fy * fx;
    out[((size_t)c * SN + i) * SN + j] = v;
}

// ---------------- inverse rotate + accumulate into cropped acc -------------
// acc[c,i,xc] += bilinear sample of U (SN x SN, zero outside) at coords for
// output pixel (i, xc+PADN) rotated by (ca,sa).
__global__ __launch_bounds__(256) void rot_bwd_k(const float* __restrict__ U,
                                                 float* __restrict__ acc,
                                                 float ca, float sa) {
    const int xc = blockIdx.x * 32 + threadIdx.x; // 0..191
    const int i  = blockIdx.y * 8 + threadIdx.y;  // 0..255
    const int c  = blockIdx.z;
    const int j  = xc + PADN;
    const float cc = (SN - 1) * 0.5f;
    float yy = (float)i - cc, xx = (float)j - cc;
    float sy = ca * yy + sa * xx + cc;
    float sx = -sa * yy + ca * xx + cc;
    float y0f = floorf(sy), x0f = floorf(sx);
    float fy = sy - y0f, fx = sx - x0f;
    int y0 = (int)y0f, x0 = (int)x0f;
    const float* __restrict__ base = U + (size_t)c * SN * SN;
    auto g = [&](int yi, int xi) -> float {
        return (yi >= 0 && yi < SN && xi >= 0 && xi < SN)
                   ? base[(size_t)yi * SN + xi] : 0.f;
    };
    float v = g(y0, x0) * (1.f - fy) * (1.f - fx)
            + g(y0, x0 + 1) * (1.f - fy) * fx
            + g(y0 + 1, x0) * fy * (1.f - fx)
            + g(y0 + 1, x0 + 1) * fy * fx;
    acc[((size_t)c * HN + i) * WN + xc] += v;
}

// ---------------- finalize: out = (C + acc) / norm[c] ----------------
__global__ __launch_bounds__(256) void final_k(float* __restrict__ outC,
                                               const float* __restrict__ acc,
                                               const float* __restrict__ norm) {
    size_t idx = (size_t)blockIdx.x * 256 + threadIdx.x;
    int c = (int)(idx / (HN * WN));
    outC[idx] = (outC[idx] + acc[idx]) / norm[c];
}

extern "C" void kernel_launch(void* const* d_in, const int* in_sizes, int n_in,
                              void* d_out, int out_size, void* d_ws, size_t ws_size,
                              hipStream_t stream) {
    const float* x    = (const float*)d_in[0];
    const float* kg   = (const float*)d_in[1];
    const float* kw   = (const float*)d_in[2];
    const float* kiso = (const float*)d_in[3];
    const float* norm = (const float*)d_in[4];

    float* C = (float*)d_out;                 // 256*256*192 = 12,582,912 floats
    float* ws = (float*)d_ws;
    const size_t IMG = (size_t)CN * HN * WN;  // 12,582,912
    const size_t PSQ = (size_t)CN * SN * SN;  // 16,777,216
    float* B   = ws;                          // IMG floats
    float* acc = ws + IMG;                    // IMG floats
    float* T   = ws + 2 * IMG;                // PSQ floats
    float* U   = T + PSQ;                     // PSQ floats
    // total ws use: 2*IMG + 2*PSQ = 58,720,256 floats = 224 MiB

    const dim3 convHGrid(HN / TH, CN), convHBlk(192);
    const dim3 convWGrid(HN / 16, CN), convW192Blk(192), convW256Blk(256);
    const dim3 rotFGrid(SN / 32, SN / 8, CN), rotBlk(32, 8);
    const dim3 rotBGrid(WN / 32, SN / 8, CN);

    // 1-2: gaussian separable conv -> C (d_out)
    conv_h_k<<<convHGrid, convHBlk, 0, stream>>>(x, kg, B);
    conv_w_k<WN, false><<<convWGrid, convW192Blk, 0, stream>>>(B, kg, C);
    // 3-4: iso separable conv -> acc
    conv_h_k<<<convHGrid, convHBlk, 0, stream>>>(C, kiso, B);
    conv_w_k<WN, false><<<convWGrid, convW192Blk, 0, stream>>>(B, kiso, acc);
    // 5: i=0 tail term (identity rotation): acc += conv_w(C, kw)
    conv_w_k<WN, true><<<convWGrid, convW192Blk, 0, stream>>>(C, kw, acc);
    // 6-11: i=1,2 tail terms
    const double a1 = 60.0 * M_PI / 180.0, a2 = 120.0 * M_PI / 180.0;
    const float c1 = (float)cos(a1), s1 = (float)sin(a1);
    const float c2 = (float)cos(a2), s2 = (float)sin(a2);

    rot_fwd_k<<<rotFGrid, rotBlk, 0, stream>>>(C, T, c1, s1);
    conv_w_k<SN, false><<<convWGrid, convW256Blk, 0, stream>>>(T, kw, U);
    rot_bwd_k<<<rotBGrid, rotBlk, 0, stream>>>(U, acc, c1, -s1);

    rot_fwd_k<<<rotFGrid, rotBlk, 0, stream>>>(C, T, c2, s2);
    conv_w_k<SN, false><<<convWGrid, convW256Blk, 0, stream>>>(T, kw, U);
    rot_bwd_k<<<rotBGrid, rotBlk, 0, stream>>>(U, acc, c2, -s2);

    // 12: out = (C + acc) / norm[c]
    final_k<<<(unsigned)(IMG / 256), 256, 0, stream>>>(C, acc, norm);
    (void)in_sizes; (void)n_in; (void)out_size; (void)ws_size;
}

// Round 2
// 1119.562 us; speedup vs baseline: 1.3486x; 1.3486x over previous
//
#include <hip/hip_runtime.h>
#include <cmath>

// Problem constants
#define CN   256   // channels (N_DIST)
#define HN   256   // H
#define WN   192   // W
#define KN   129   // kernel taps
#define RN   64    // radius
#define SN   256   // padded size
#define PADN 32    // (SN - WN)/2

// ================= conv along W (last axis), LDS-tiled =================
// Block: 256 thr = 4 waves. Tile: 64 rows x 64 output cols.
// LDS: 64 x (64+128) window, pitch 193 (odd -> conflict-free for lane=row).
// Zero-padded halo staged into LDS => branch-free 129-tap main loop.
template <int WD, bool ACC>
__global__ __launch_bounds__(256) void conv_w_lds(const float* __restrict__ in,
                                                  const float* __restrict__ kern,
                                                  float* __restrict__ out) {
    __shared__ float lds[64 * 193];
    const int tid = threadIdx.x;
    const int x0  = blockIdx.x * 64;
    const int h0  = blockIdx.y * 64;
    const int c   = blockIdx.z;
    const float* __restrict__ in_c = in + ((size_t)c * HN + h0) * WD;

    // stage 64 rows x 192 cols (global cols x0-64 .. x0+127), zeros outside
    for (int idx = tid; idx < 64 * 192; idx += 256) {
        int r = idx / 192, col = idx - r * 192;
        int g = x0 + col - 64;
        float v = (g >= 0 && g < WD) ? in_c[(size_t)r * WD + g] : 0.f;
        lds[r * 193 + col] = v;
    }
    __syncthreads();

    const int wv = tid >> 6;        // wave 0..3 -> output col chunk
    const int l  = tid & 63;        // lane = row
    const float* __restrict__ krow = kern + c * KN;
    const int base = l * 193 + wv * 16;   // window pos 0 <-> global col x0+wv*16-64

    float wreg[16], acc[16];
#pragma unroll
    for (int t = 0; t < 16; ++t) { wreg[t] = lds[base + t]; acc[t] = 0.f; }

    for (int chunk = 0; chunk < 8; ++chunk) {
        const int jj0 = chunk * 16;
#pragma unroll
        for (int u = 0; u < 16; ++u) {
            const float kj = krow[jj0 + u];
#pragma unroll
            for (int t = 0; t < 16; ++t)
                acc[t] = fmaf(wreg[(u + t) & 15], kj, acc[t]);
            wreg[u] = lds[base + jj0 + u + 16];   // refill oldest
        }
    }
    {   // final tap jj = 128
        const float kj = krow[128];
#pragma unroll
        for (int t = 0; t < 16; ++t) acc[t] = fmaf(wreg[t], kj, acc[t]);
    }

    float* __restrict__ orow = out + ((size_t)c * HN + h0 + l) * WD + x0 + wv * 16;
#pragma unroll
    for (int t = 0; t < 16; ++t) {
        if (ACC) orow[t] += acc[t];
        else     orow[t]  = acc[t];
    }
}

// ================= conv along H (axis 1), LDS-tiled =================
// Block: 256 thr = 4 waves. Tile: 64 output rows x 64 cols; lane = col.
// LDS: (64+128) rows x 64 cols; lane-consecutive access is conflict-free.
__global__ __launch_bounds__(256) void conv_h_lds(const float* __restrict__ in,
                                                  const float* __restrict__ kern,
                                                  float* __restrict__ out) {
    __shared__ float lds[192 * 64];
    const int tid = threadIdx.x;
    const int x0  = blockIdx.x * 64;
    const int h0  = blockIdx.y * 64;
    const int c   = blockIdx.z;
    const float* __restrict__ in_c = in + (size_t)c * HN * WN;

    // stage rows h0-64 .. h0+127 x 64 cols, zeros outside [0,HN)
    for (int idx = tid; idx < 192 * 64; idx += 256) {
        int r = idx >> 6, col = idx & 63;
        int g = h0 + r - 64;
        float v = (g >= 0 && g < HN) ? in_c[(size_t)g * WN + x0 + col] : 0.f;
        lds[r * 64 + col] = v;
    }
    __syncthreads();

    const int wv = tid >> 6;        // wave -> output row chunk
    const int l  = tid & 63;        // lane = col
    const float* __restrict__ krow = kern + c * KN;
    const int baseRow = wv * 16;    // window row 0 <-> global row h0+wv*16-64

    float wreg[16], acc[16];
#pragma unroll
    for (int t = 0; t < 16; ++t) { wreg[t] = lds[(baseRow + t) * 64 + l]; acc[t] = 0.f; }

    for (int chunk = 0; chunk < 8; ++chunk) {
        const int jj0 = chunk * 16;
#pragma unroll
        for (int u = 0; u < 16; ++u) {
            const float kj = krow[jj0 + u];
#pragma unroll
            for (int t = 0; t < 16; ++t)
                acc[t] = fmaf(wreg[(u + t) & 15], kj, acc[t]);
            wreg[u] = lds[(baseRow + jj0 + u + 16) * 64 + l];
        }
    }
    {
        const float kj = krow[128];
#pragma unroll
        for (int t = 0; t < 16; ++t) acc[t] = fmaf(wreg[t], kj, acc[t]);
    }

    float* __restrict__ ob = out + ((size_t)c * HN + h0 + wv * 16) * WN + x0 + l;
#pragma unroll
    for (int t = 0; t < 16; ++t) ob[(size_t)t * WN] = acc[t];
}

// ---------------- forward rotate of implicitly-padded C ----------------
__global__ __launch_bounds__(256) void rot_fwd_k(const float* __restrict__ Cin,
                                                 float* __restrict__ out,
                                                 float ca, float sa) {
    const int j = blockIdx.x * 32 + threadIdx.x;  // 0..255
    const int i = blockIdx.y * 8 + threadIdx.y;   // 0..255
    const int c = blockIdx.z;
    const float cc = (SN - 1) * 0.5f;             // 127.5
    float yy = (float)i - cc, xx = (float)j - cc;
    float sy = ca * yy + sa * xx + cc;
    float sx = -sa * yy + ca * xx + cc;
    float y0f = floorf(sy), x0f = floorf(sx);
    float fy = sy - y0f, fx = sx - x0f;
    int y0 = (int)y0f, x0 = (int)x0f;
    const float* __restrict__ base = Cin + (size_t)c * HN * WN;
    auto g = [&](int yi, int xi) -> float {
        int p = xi - PADN;
        return (yi >= 0 && yi < SN && p >= 0 && p < WN)
                   ? base[(size_t)yi * WN + p] : 0.f;
    };
    float v = g(y0, x0) * (1.f - fy) * (1.f - fx)
            + g(y0, x0 + 1) * (1.f - fy) * fx
            + g(y0 + 1, x0) * fy * (1.f - fx)
            + g(y0 + 1, x0 + 1) * fy * fx;
    out[((size_t)c * SN + i) * SN + j] = v;
}

// ---------------- inverse rotate + accumulate into cropped acc -------------
__global__ __launch_bounds__(256) void rot_bwd_k(const float* __restrict__ U,
                                                 float* __restrict__ acc,
                                                 float ca, float sa) {
    const int xc = blockIdx.x * 32 + threadIdx.x; // 0..191
    const int i  = blockIdx.y * 8 + threadIdx.y;  // 0..255
    const int c  = blockIdx.z;
    const int j  = xc + PADN;
    const float cc = (SN - 1) * 0.5f;
    float yy = (float)i - cc, xx = (float)j - cc;
    float sy = ca * yy + sa * xx + cc;
    float sx = -sa * yy + ca * xx + cc;
    float y0f = floorf(sy), x0f = floorf(sx);
    float fy = sy - y0f, fx = sx - x0f;
    int y0 = (int)y0f, x0 = (int)x0f;
    const float* __restrict__ base = U + (size_t)c * SN * SN;
    auto g = [&](int yi, int xi) -> float {
        return (yi >= 0 && yi < SN && xi >= 0 && xi < SN)
                   ? base[(size_t)yi * SN + xi] : 0.f;
    };
    float v = g(y0, x0) * (1.f - fy) * (1.f - fx)
            + g(y0, x0 + 1) * (1.f - fy) * fx
            + g(y0 + 1, x0) * fy * (1.f - fx)
            + g(y0 + 1, x0 + 1) * fy * fx;
    acc[((size_t)c * HN + i) * WN + xc] += v;
}

// ---------------- finalize: out = (C + acc) / norm[c] ----------------
__global__ __launch_bounds__(256) void final_k(float* __restrict__ outC,
                                               const float* __restrict__ acc,
                                               const float* __restrict__ norm) {
    size_t idx = (size_t)blockIdx.x * 256 + threadIdx.x;
    int c = (int)(idx / (HN * WN));
    outC[idx] = (outC[idx] + acc[idx]) / norm[c];
}

extern "C" void kernel_launch(void* const* d_in, const int* in_sizes, int n_in,
                              void* d_out, int out_size, void* d_ws, size_t ws_size,
                              hipStream_t stream) {
    const float* x    = (const float*)d_in[0];
    const float* kg   = (const float*)d_in[1];
    const float* kw   = (const float*)d_in[2];
    const float* kiso = (const float*)d_in[3];
    const float* norm = (const float*)d_in[4];

    float* C = (float*)d_out;                 // 256*256*192 floats
    float* ws = (float*)d_ws;
    const size_t IMG = (size_t)CN * HN * WN;  // 12,582,912
    const size_t PSQ = (size_t)CN * SN * SN;  // 16,777,216
    float* B   = ws;                          // IMG
    float* acc = ws + IMG;                    // IMG
    float* T   = ws + 2 * IMG;                // PSQ
    float* U   = T + PSQ;                     // PSQ

    const dim3 convHGrid(WN / 64, HN / 64, CN), blk256(256);
    const dim3 convW192Grid(WN / 64, HN / 64, CN);
    const dim3 convW256Grid(SN / 64, HN / 64, CN);
    const dim3 rotFGrid(SN / 32, SN / 8, CN), rotBlk(32, 8);
    const dim3 rotBGrid(WN / 32, SN / 8, CN);

    // 1-2: gaussian separable conv -> C (d_out)
    conv_h_lds<<<convHGrid, blk256, 0, stream>>>(x, kg, B);
    conv_w_lds<WN, false><<<convW192Grid, blk256, 0, stream>>>(B, kg, C);
    // 3-4: iso separable conv -> acc
    conv_h_lds<<<convHGrid, blk256, 0, stream>>>(C, kiso, B);
    conv_w_lds<WN, false><<<convW192Grid, blk256, 0, stream>>>(B, kiso, acc);
    // 5: i=0 tail term (identity rotation): acc += conv_w(C, kw)
    conv_w_lds<WN, true><<<convW192Grid, blk256, 0, stream>>>(C, kw, acc);
    // 6-11: i=1,2 tail terms
    const double a1 = 60.0 * M_PI / 180.0, a2 = 120.0 * M_PI / 180.0;
    const float c1 = (float)cos(a1), s1 = (float)sin(a1);
    const float c2 = (float)cos(a2), s2 = (float)sin(a2);

    rot_fwd_k<<<rotFGrid, rotBlk, 0, stream>>>(C, T, c1, s1);
    conv_w_lds<SN, false><<<convW256Grid, blk256, 0, stream>>>(T, kw, U);
    rot_bwd_k<<<rotBGrid, rotBlk, 0, stream>>>(U, acc, c1, -s1);

    rot_fwd_k<<<rotFGrid, rotBlk, 0, stream>>>(C, T, c2, s2);
    conv_w_lds<SN, false><<<convW256Grid, blk256, 0, stream>>>(T, kw, U);
    rot_bwd_k<<<rotBGrid, rotBlk, 0, stream>>>(U, acc, c2, -s2);

    // 12: out = (C + acc) / norm[c]
    final_k<<<(unsigned)(IMG / 256), 256, 0, stream>>>(C, acc, norm);
    (void)in_sizes; (void)n_in; (void)out_size; (void)ws_size;
}